// Round 2
// baseline (9541.340 us; speedup 1.0000x reference)
//
#include <hip/hip_runtime.h>
#include <hip/hip_bf16.h>

typedef unsigned short u16;
typedef unsigned int u32;

#define DEVFN static __device__ __forceinline__

DEVFN float b2f(u16 u) { return __uint_as_float(((u32)u) << 16); }
DEVFN void up2(u32 w, float& a, float& b) {
  a = __uint_as_float(w << 16);
  b = __uint_as_float(w & 0xffff0000u);
}
DEVFN u16 f2b(float f) {
  u32 u = __float_as_uint(f);
  return (u16)((u + 0x7fffu + ((u >> 16) & 1u)) >> 16);
}

// Detect whether buffer holds packed bf16 (vs fp32). For bf16 data ~N(0,1),
// the low u16 of each u32 is a bf16 with exponent in [97,132]. For fp32 data
// the low u16 is ~uniform mantissa bits: P(exponent-field in range) ~ 0.14,
// so P(count>=48 of 64) ~ 0. Block-uniform, deterministic.
DEVFN bool probe_bf16(const void* x) {
  const u32* p = (const u32*)x;
  int cnt = 0;
  for (int i = 0; i < 64; i++) {
    u32 lo = p[i] & 0xffffu;
    u32 e = (lo >> 7) & 0xffu;
    cnt += ((lo == 0u) || (e >= 97u && e <= 132u)) ? 1 : 0;
  }
  return cnt >= 48;
}

// dtype-dual global accessors (element index i; bf=true -> bf16, else fp32)
DEVFN float ld1(const void* p, size_t i, bool bf) {
  return bf ? b2f(((const u16*)p)[i]) : ((const float*)p)[i];
}
DEVFN void ld2(const void* p, size_t i, bool bf, float& a, float& b) {
  if (bf) up2(*(const u32*)((const u16*)p + i), a, b);
  else { float2 t = *(const float2*)((const float*)p + i); a = t.x; b = t.y; }
}
DEVFN void ld8(const void* p, size_t i, bool bf, float* f) {
  if (bf) {
    uint4 q = *(const uint4*)((const u16*)p + i);
    up2(q.x, f[0], f[1]); up2(q.y, f[2], f[3]);
    up2(q.z, f[4], f[5]); up2(q.w, f[6], f[7]);
  } else {
    float4 t0 = *(const float4*)((const float*)p + i);
    float4 t1 = *(const float4*)((const float*)p + i + 4);
    f[0]=t0.x; f[1]=t0.y; f[2]=t0.z; f[3]=t0.w;
    f[4]=t1.x; f[5]=t1.y; f[6]=t1.z; f[7]=t1.w;
  }
}
DEVFN void st2(void* p, size_t i, bool bf, float a, float b) {
  if (bf) *(u32*)((u16*)p + i) = (u32)f2b(a) | ((u32)f2b(b) << 16);
  else *(float2*)((float*)p + i) = make_float2(a, b);
}

// Config: B=8 H=64 W=512 C=192 NH=6 HD=32 WH=4 WW=8 SH=2 SW=4
// N=32 tokens/window, windows 16x64=1024 per image, 8192 total.

// ---------------------------------------------------------------------------
// Kernel A: shifted-window attention block. One block per window (256 thr).
// Computes x1 = x + proj(attn(LN1(window(x)))) and scatters to d_out.
// ---------------------------------------------------------------------------
__launch_bounds__(256, 2)
__global__ void swin_attn_kernel(
    const void* __restrict__ x, const void* __restrict__ g1, const void* __restrict__ be1,
    const void* __restrict__ wqkv, const void* __restrict__ bqkv,
    const void* __restrict__ wproj, const void* __restrict__ bproj,
    const void* __restrict__ btab, void* __restrict__ out)
{
  __shared__ u16   wnT[192][32];      // LN1 output, [channel][token], bf16
  __shared__ float qs[2][32][32];     // per head-pair
  __shared__ float ks[2][32][32];
  __shared__ float vs[2][32][32];
  __shared__ float Ps[2][32][32];     // softmax probs
  __shared__ u16   aoT[192][32];      // attention out, [channel][token]

  const bool bf = probe_bf16(x);
  const int tid = threadIdx.x;
  const int wid = blockIdx.x;
  const int b   = wid >> 10;
  const int wli = wid & 1023;
  const int whi = wli >> 6;   // window row 0..15
  const int wwi = wli & 63;   // window col 0..63

  // shifted-window gather position -> flat token index in x (bijection)
  auto gtok = [&](int n) -> int {
    const int r = n >> 3, c = n & 7;
    const int ho = (whi * 4 + r + 2) & 63;
    const int wo = (wwi * 8 + c + 4) & 511;
    return (b << 15) + ho * 512 + wo;
  };

  // ---- Phase 1: gather + LayerNorm1 -> wnT ----
  {
    const int n = tid >> 3, g = tid & 7;
    const int c0 = g * 24;
    const size_t base = (size_t)gtok(n) * 192 + c0;
    float v[24];
    ld8(x, base, bf, v); ld8(x, base + 8, bf, v + 8); ld8(x, base + 16, bf, v + 16);
    float s = 0.f, ss = 0.f;
#pragma unroll
    for (int i = 0; i < 24; i++) { s += v[i]; ss += v[i] * v[i]; }
#pragma unroll
    for (int o = 1; o < 8; o <<= 1) { s += __shfl_xor(s, o); ss += __shfl_xor(ss, o); }
    const float mu = s * (1.f / 192.f);
    const float rstd = rsqrtf(ss * (1.f / 192.f) - mu * mu + 1e-5f);
#pragma unroll
    for (int i = 0; i < 24; i++) {
      const int c = c0 + i;
      wnT[c][n] = f2b((v[i] - mu) * rstd * ld1(g1, c, bf) + ld1(be1, c, bf));
    }
  }
  __syncthreads();

  const float scale = 0.17677669529663687f;  // 1/sqrt(32)

  for (int hp = 0; hp < 3; ++hp) {           // head pairs (2*hp, 2*hp+1)
    // ---- qkv GEMM for this head pair: 32 tok x 192 cols, K=192 ----
    if (tid < 192) {
      const int tg = tid / 24;          // 4-token group
      const int cg = tid % 24;          // 8-col group
      const int sel = cg >> 3;          // 0=q 1=k 2=v
      const int hh = (cg >> 2) & 1;     // head within pair
      const int dbase = 8 * (cg & 3);
      const int jcb = sel * 192 + (2 * hp + hh) * 32 + dbase;  // col in w_qkv
      float acc[4][8] = {};
      for (int k = 0; k < 192; k++) {
        const uint2 hw = *reinterpret_cast<const uint2*>(&wnT[k][4 * tg]);
        float a0, a1, a2, a3; up2(hw.x, a0, a1); up2(hw.y, a2, a3);
        float wf[8];
        ld8(wqkv, (size_t)k * 576 + jcb, bf, wf);
#pragma unroll
        for (int jj = 0; jj < 8; jj++) {
          acc[0][jj] += a0 * wf[jj];
          acc[1][jj] += a1 * wf[jj];
          acc[2][jj] += a2 * wf[jj];
          acc[3][jj] += a3 * wf[jj];
        }
      }
      float bb[8];
#pragma unroll
      for (int jj = 0; jj < 8; jj++) bb[jj] = ld1(bqkv, jcb + jj, bf);
      float* dst = (sel == 0) ? &qs[0][0][0] : (sel == 1) ? &ks[0][0][0] : &vs[0][0][0];
#pragma unroll
      for (int t = 0; t < 4; t++) {
        const int n = 4 * tg + t;
        float4 o0, o1;
        o0.x = acc[t][0] + bb[0]; o0.y = acc[t][1] + bb[1];
        o0.z = acc[t][2] + bb[2]; o0.w = acc[t][3] + bb[3];
        o1.x = acc[t][4] + bb[4]; o1.y = acc[t][5] + bb[5];
        o1.z = acc[t][6] + bb[6]; o1.w = acc[t][7] + bb[7];
        float* base = dst + hh * 1024 + n * 32 + dbase;
        *reinterpret_cast<float4*>(base) = o0;
        *reinterpret_cast<float4*>(base + 4) = o1;
      }
    }
    __syncthreads();

    // ---- S = q k^T * scale + bias + mask ; softmax over m ----
    {
      const int hn = tid >> 2, mg = tid & 3;
      const int hh = hn >> 5, n = hn & 31;
      const int hg = 2 * hp + hh;
      float qr[32];
      const float4* qp = reinterpret_cast<const float4*>(&qs[hh][n][0]);
#pragma unroll
      for (int i = 0; i < 8; i++) {
        const float4 t4 = qp[i];
        qr[4 * i] = t4.x; qr[4 * i + 1] = t4.y; qr[4 * i + 2] = t4.z; qr[4 * i + 3] = t4.w;
      }
      const int rn = n >> 3, cn = n & 7;
      const bool rhn = (whi == 15) && (rn >= 2);
      const bool rwn = (wwi == 63) && (cn >= 4);
      float sv[8];
#pragma unroll
      for (int mi = 0; mi < 8; mi++) {
        const int m = 8 * mg + mi;
        const float4* kp = reinterpret_cast<const float4*>(&ks[hh][m][0]);
        float dot = 0.f;
#pragma unroll
        for (int i = 0; i < 8; i++) {
          const float4 kk = kp[i];
          dot += qr[4 * i] * kk.x + qr[4 * i + 1] * kk.y
               + qr[4 * i + 2] * kk.z + qr[4 * i + 3] * kk.w;
        }
        const int rm = m >> 3, cm = m & 7;
        const float bias = ld1(btab, (size_t)((rn - rm + 3) * 15 + (cn - cm + 7)) * 6 + hg, bf);
        const bool rhm = (whi == 15) && (rm >= 2);
        const bool rwm = (wwi == 63) && (cm >= 4);
        const float msk = ((rhn != rhm) || (rwn != rwm)) ? -100.f : 0.f;
        sv[mi] = dot * scale + bias + msk;
      }
      float mx = sv[0];
#pragma unroll
      for (int mi = 1; mi < 8; mi++) mx = fmaxf(mx, sv[mi]);
      mx = fmaxf(mx, __shfl_xor(mx, 1));
      mx = fmaxf(mx, __shfl_xor(mx, 2));
      float sum = 0.f;
#pragma unroll
      for (int mi = 0; mi < 8; mi++) { sv[mi] = __expf(sv[mi] - mx); sum += sv[mi]; }
      sum += __shfl_xor(sum, 1);
      sum += __shfl_xor(sum, 2);
      const float inv = 1.f / sum;
      float4 p0, p1;
      p0.x = sv[0] * inv; p0.y = sv[1] * inv; p0.z = sv[2] * inv; p0.w = sv[3] * inv;
      p1.x = sv[4] * inv; p1.y = sv[5] * inv; p1.z = sv[6] * inv; p1.w = sv[7] * inv;
      *reinterpret_cast<float4*>(&Ps[hh][n][8 * mg]) = p0;
      *reinterpret_cast<float4*>(&Ps[hh][n][8 * mg + 4]) = p1;
    }
    __syncthreads();

    // ---- out = P @ V -> aoT ----
    {
      const int hn = tid >> 2, mg = tid & 3;
      const int hh = hn >> 5, n = hn & 31, d0 = 8 * mg;
      const int hg = 2 * hp + hh;
      float pr[32];
      const float4* pp = reinterpret_cast<const float4*>(&Ps[hh][n][0]);
#pragma unroll
      for (int i = 0; i < 8; i++) {
        const float4 t4 = pp[i];
        pr[4 * i] = t4.x; pr[4 * i + 1] = t4.y; pr[4 * i + 2] = t4.z; pr[4 * i + 3] = t4.w;
      }
      float acc[8] = {};
#pragma unroll
      for (int m = 0; m < 32; m++) {
        const float4 v0 = *reinterpret_cast<const float4*>(&vs[hh][m][d0]);
        const float4 v1 = *reinterpret_cast<const float4*>(&vs[hh][m][d0 + 4]);
        const float p = pr[m];
        acc[0] += p * v0.x; acc[1] += p * v0.y; acc[2] += p * v0.z; acc[3] += p * v0.w;
        acc[4] += p * v1.x; acc[5] += p * v1.y; acc[6] += p * v1.z; acc[7] += p * v1.w;
      }
#pragma unroll
      for (int j = 0; j < 8; j++) aoT[hg * 32 + d0 + j][n] = f2b(acc[j]);
    }
    __syncthreads();
  }

  // ---- proj + residual, scatter to d_out ----
  {
    const int tg = tid >> 5, cg = tid & 31;
    const int j0 = 6 * cg;
    float bb[6];
#pragma unroll
    for (int j = 0; j < 6; j++) bb[j] = ld1(bproj, j0 + j, bf);
    float acc[4][6] = {};
    for (int k = 0; k < 192; k++) {
      const uint2 aw = *reinterpret_cast<const uint2*>(&aoT[k][4 * tg]);
      float a0, a1, a2, a3; up2(aw.x, a0, a1); up2(aw.y, a2, a3);
      float wf[6];
      const size_t wi = (size_t)k * 192 + j0;
      ld2(wproj, wi,     bf, wf[0], wf[1]);
      ld2(wproj, wi + 2, bf, wf[2], wf[3]);
      ld2(wproj, wi + 4, bf, wf[4], wf[5]);
#pragma unroll
      for (int jj = 0; jj < 6; jj++) {
        acc[0][jj] += a0 * wf[jj];
        acc[1][jj] += a1 * wf[jj];
        acc[2][jj] += a2 * wf[jj];
        acc[3][jj] += a3 * wf[jj];
      }
    }
#pragma unroll
    for (int t = 0; t < 4; t++) {
      const size_t gt = (size_t)gtok(4 * tg + t);
      const size_t xb = gt * 192 + j0;
      float xv[6];
      ld2(x, xb,     bf, xv[0], xv[1]);
      ld2(x, xb + 2, bf, xv[2], xv[3]);
      ld2(x, xb + 4, bf, xv[4], xv[5]);
#pragma unroll
      for (int q = 0; q < 3; q++) {
        const float r0 = xv[2 * q]     + acc[t][2 * q]     + bb[2 * q];
        const float r1 = xv[2 * q + 1] + acc[t][2 * q + 1] + bb[2 * q + 1];
        st2(out, xb + 2 * q, bf, r0, r1);
      }
    }
  }
}

// ---------------------------------------------------------------------------
// Kernel B: MLP block, in-place on d_out. 64 tokens per block (256 thr).
// out = x1 + gelu(LN2(x1) @ w1 + bm1) @ w2 + bm2
// ---------------------------------------------------------------------------
__launch_bounds__(256, 2)
__global__ void swin_mlp_kernel(
    const void* __restrict__ xp,   // original x, for dtype probe only
    void* __restrict__ io, const void* __restrict__ g2, const void* __restrict__ be2,
    const void* __restrict__ w1, const void* __restrict__ bm1,
    const void* __restrict__ w2, const void* __restrict__ bm2)
{
  __shared__ u16   hT[192][64];     // LN2 output, [channel][token], bf16
  __shared__ float hidT[128][64];   // hidden chunk, [hid_ch][token], fp32

  const bool bf = probe_bf16(xp);
  const int tid = threadIdx.x;
  const size_t tok0 = (size_t)blockIdx.x * 64;

  // ---- LN2 ----
  {
    const int t = tid >> 2, g = tid & 3;
    const int c0 = 48 * g;
    const size_t base = (tok0 + t) * 192 + c0;
    float v[48];
#pragma unroll
    for (int i = 0; i < 6; i++) ld8(io, base + 8 * i, bf, v + 8 * i);
    float s = 0.f, ss = 0.f;
#pragma unroll
    for (int i = 0; i < 48; i++) { s += v[i]; ss += v[i] * v[i]; }
#pragma unroll
    for (int o = 1; o < 4; o <<= 1) { s += __shfl_xor(s, o); ss += __shfl_xor(ss, o); }
    const float mu = s * (1.f / 192.f);
    const float rstd = rsqrtf(ss * (1.f / 192.f) - mu * mu + 1e-5f);
#pragma unroll
    for (int i = 0; i < 48; i++) {
      const int c = c0 + i;
      hT[c][t] = f2b((v[i] - mu) * rstd * ld1(g2, c, bf) + ld1(be2, c, bf));
    }
  }
  __syncthreads();

  const int tg = tid >> 4, cg = tid & 15;   // 16 token-groups x 16 col-groups
  float oacc[4][12] = {};

  for (int ch = 0; ch < 6; ++ch) {
    // ---- mlp1 chunk: hidden cols [128*ch, 128*ch+128) ----
    const int j0 = 128 * ch + 8 * cg;
    float ha[4][8] = {};
    for (int k = 0; k < 192; k++) {
      const uint2 hw = *reinterpret_cast<const uint2*>(&hT[k][4 * tg]);
      float a0, a1, a2, a3; up2(hw.x, a0, a1); up2(hw.y, a2, a3);
      float wf[8];
      ld8(w1, (size_t)k * 768 + j0, bf, wf);
#pragma unroll
      for (int jj = 0; jj < 8; jj++) {
        ha[0][jj] += a0 * wf[jj];
        ha[1][jj] += a1 * wf[jj];
        ha[2][jj] += a2 * wf[jj];
        ha[3][jj] += a3 * wf[jj];
      }
    }
#pragma unroll
    for (int jj = 0; jj < 8; jj++) {
      const float bias = ld1(bm1, j0 + jj, bf);
#pragma unroll
      for (int t = 0; t < 4; t++) {
        const float hv = ha[t][jj] + bias;
        hidT[8 * cg + jj][4 * tg + t] = 0.5f * hv * (1.f + erff(hv * 0.70710678118654752f));
      }
    }
    __syncthreads();

    // ---- mlp2 chunk accumulate ----
    for (int k = 0; k < 128; k++) {
      const float4 hv = *reinterpret_cast<const float4*>(&hidT[k][4 * tg]);
      const size_t wi = (size_t)(128 * ch + k) * 192 + 12 * cg;
      float wf[12];
      ld2(w2, wi,      bf, wf[0],  wf[1]);
      ld2(w2, wi + 2,  bf, wf[2],  wf[3]);
      ld2(w2, wi + 4,  bf, wf[4],  wf[5]);
      ld2(w2, wi + 6,  bf, wf[6],  wf[7]);
      ld2(w2, wi + 8,  bf, wf[8],  wf[9]);
      ld2(w2, wi + 10, bf, wf[10], wf[11]);
#pragma unroll
      for (int jj = 0; jj < 12; jj++) {
        oacc[0][jj] += hv.x * wf[jj];
        oacc[1][jj] += hv.y * wf[jj];
        oacc[2][jj] += hv.z * wf[jj];
        oacc[3][jj] += hv.w * wf[jj];
      }
    }
    __syncthreads();
  }

  // ---- epilogue: + bm2 + x1 residual, write back (in-place safe per-thread) ----
  float bb2[12];
#pragma unroll
  for (int jj = 0; jj < 12; jj++) bb2[jj] = ld1(bm2, 12 * cg + jj, bf);
#pragma unroll
  for (int t = 0; t < 4; t++) {
    const size_t base = (tok0 + 4 * tg + t) * 192 + 12 * cg;
    float xv[12];
    ld2(io, base,      bf, xv[0],  xv[1]);
    ld2(io, base + 2,  bf, xv[2],  xv[3]);
    ld2(io, base + 4,  bf, xv[4],  xv[5]);
    ld2(io, base + 6,  bf, xv[6],  xv[7]);
    ld2(io, base + 8,  bf, xv[8],  xv[9]);
    ld2(io, base + 10, bf, xv[10], xv[11]);
#pragma unroll
    for (int q = 0; q < 6; q++) {
      const float r0 = xv[2 * q]     + oacc[t][2 * q]     + bb2[2 * q];
      const float r1 = xv[2 * q + 1] + oacc[t][2 * q + 1] + bb2[2 * q + 1];
      st2(io, base + 2 * q, bf, r0, r1);
    }
  }
}

extern "C" void kernel_launch(void* const* d_in, const int* in_sizes, int n_in,
                              void* d_out, int out_size, void* d_ws, size_t ws_size,
                              hipStream_t stream) {
  const void* x     = d_in[0];
  // d_in[1] = H (64), d_in[2] = W (512): static config, unused
  const void* g1    = d_in[3];
  const void* be1   = d_in[4];
  const void* wqkv  = d_in[5];
  const void* bqkv  = d_in[6];
  const void* wproj = d_in[7];
  const void* bproj = d_in[8];
  const void* btab  = d_in[9];
  const void* g2    = d_in[10];
  const void* be2   = d_in[11];
  const void* w1    = d_in[12];
  const void* bm1   = d_in[13];
  const void* w2    = d_in[14];
  const void* bm2   = d_in[15];

  // K_A: one block per window (8*16*64 = 8192), writes x1 into d_out
  swin_attn_kernel<<<8192, 256, 0, stream>>>(x, g1, be1, wqkv, bqkv, wproj, bproj, btab, d_out);
  // K_B: MLP in-place on d_out, 262144 tokens / 64 per block
  swin_mlp_kernel<<<4096, 256, 0, stream>>>(x, d_out, g2, be2, w1, bm1, w2, bm2);
}

// Round 3
// 4225.747 us; speedup vs baseline: 2.2579x; 2.2579x over previous
//
#include <hip/hip_runtime.h>
#include <hip/hip_bf16.h>

typedef unsigned short u16;
typedef unsigned int u32;
typedef __attribute__((ext_vector_type(8))) short short8;   // 8 bf16 (4 VGPRs)
typedef __attribute__((ext_vector_type(4))) float f32x4;    // MFMA acc

#define DEVFN static __device__ __forceinline__

DEVFN float b2f(u16 u) { return __uint_as_float(((u32)u) << 16); }
DEVFN void up2(u32 w, float& a, float& b) {
  a = __uint_as_float(w << 16);
  b = __uint_as_float(w & 0xffff0000u);
}
DEVFN u16 f2b(float f) {
  u32 u = __float_as_uint(f);
  return (u16)((u + 0x7fffu + ((u >> 16) & 1u)) >> 16);
}

// Detect whether buffer holds packed bf16 (vs fp32). Block-uniform, deterministic.
DEVFN bool probe_bf16(const void* x) {
  const u32* p = (const u32*)x;
  int cnt = 0;
  for (int i = 0; i < 64; i++) {
    u32 lo = p[i] & 0xffffu;
    u32 e = (lo >> 7) & 0xffu;
    cnt += ((lo == 0u) || (e >= 97u && e <= 132u)) ? 1 : 0;
  }
  return cnt >= 48;
}

// dtype-dual global accessors
DEVFN float ld1(const void* p, size_t i, bool bf) {
  return bf ? b2f(((const u16*)p)[i]) : ((const float*)p)[i];
}
DEVFN void st1(void* p, size_t i, bool bf, float v) {
  if (bf) ((u16*)p)[i] = f2b(v); else ((float*)p)[i] = v;
}
DEVFN void ld2(const void* p, size_t i, bool bf, float& a, float& b) {
  if (bf) up2(*(const u32*)((const u16*)p + i), a, b);
  else { float2 t = *(const float2*)((const float*)p + i); a = t.x; b = t.y; }
}
DEVFN void ld8(const void* p, size_t i, bool bf, float* f) {
  if (bf) {
    uint4 q = *(const uint4*)((const u16*)p + i);
    up2(q.x, f[0], f[1]); up2(q.y, f[2], f[3]);
    up2(q.z, f[4], f[5]); up2(q.w, f[6], f[7]);
  } else {
    float4 t0 = *(const float4*)((const float*)p + i);
    float4 t1 = *(const float4*)((const float*)p + i + 4);
    f[0]=t0.x; f[1]=t0.y; f[2]=t0.z; f[3]=t0.w;
    f[4]=t1.x; f[5]=t1.y; f[6]=t1.z; f[7]=t1.w;
  }
}
DEVFN void st2(void* p, size_t i, bool bf, float a, float b) {
  if (bf) *(u32*)((u16*)p + i) = (u32)f2b(a) | ((u32)f2b(b) << 16);
  else *(float2*)((float*)p + i) = make_float2(a, b);
}

DEVFN short8 lds16(const u16* p) { return *reinterpret_cast<const short8*>(p); }
DEVFN short8 gld16(const u16* p) { return *reinterpret_cast<const short8*>(p); }

// tanh-approx GELU; |err| <= ~3e-3 vs exact erf-GELU
DEVFN float gelu_t(float x) {
  const float z = x * (0.7978845608f + 0.0356774081f * x * x);
  const float e = __expf(2.f * z);
  const float t = 1.f - 2.f / (e + 1.f);
  return 0.5f * x * (1.f + t);
}

// Config: B=8 H=64 W=512 C=192 NH=6 HD=32 WH=4 WW=8 SH=2 SW=4
// N=32 tokens/window, 8192 windows total. Tokens = 262144.

// ---------------------------------------------------------------------------
// Weight transpose into d_ws (bf16 always):
//   ws[0 .. 147455]        = w1t[768][192],  w1t[j][k] = w1[k][j]
//   ws[147456 .. 294911]   = w2t[192][768],  w2t[c][h] = w2[h][c]
// ---------------------------------------------------------------------------
__global__ void transpose_weights(const void* __restrict__ w1,
                                  const void* __restrict__ w2,
                                  u16* __restrict__ ws)
{
  const bool bf = probe_bf16(w1);
  const int idx = blockIdx.x * 256 + threadIdx.x;   // 0 .. 294911
  if (idx < 147456) {
    const int j = idx / 192, k = idx - 192 * j;
    ws[idx] = f2b(ld1(w1, (size_t)k * 768 + j, bf));
  } else {
    const int i2 = idx - 147456;
    const int c = i2 / 768, h = i2 - 768 * c;
    ws[idx] = f2b(ld1(w2, (size_t)h * 192 + c, bf));
  }
}

// ---------------------------------------------------------------------------
// Kernel A: shifted-window attention block (unchanged from round 2).
// ---------------------------------------------------------------------------
__launch_bounds__(256, 2)
__global__ void swin_attn_kernel(
    const void* __restrict__ x, const void* __restrict__ g1, const void* __restrict__ be1,
    const void* __restrict__ wqkv, const void* __restrict__ bqkv,
    const void* __restrict__ wproj, const void* __restrict__ bproj,
    const void* __restrict__ btab, void* __restrict__ out)
{
  __shared__ u16   wnT[192][32];
  __shared__ float qs[2][32][32];
  __shared__ float ks[2][32][32];
  __shared__ float vs[2][32][32];
  __shared__ float Ps[2][32][32];
  __shared__ u16   aoT[192][32];

  const bool bf = probe_bf16(x);
  const int tid = threadIdx.x;
  const int wid = blockIdx.x;
  const int b   = wid >> 10;
  const int wli = wid & 1023;
  const int whi = wli >> 6;
  const int wwi = wli & 63;

  auto gtok = [&](int n) -> int {
    const int r = n >> 3, c = n & 7;
    const int ho = (whi * 4 + r + 2) & 63;
    const int wo = (wwi * 8 + c + 4) & 511;
    return (b << 15) + ho * 512 + wo;
  };

  {
    const int n = tid >> 3, g = tid & 7;
    const int c0 = g * 24;
    const size_t base = (size_t)gtok(n) * 192 + c0;
    float v[24];
    ld8(x, base, bf, v); ld8(x, base + 8, bf, v + 8); ld8(x, base + 16, bf, v + 16);
    float s = 0.f, ss = 0.f;
#pragma unroll
    for (int i = 0; i < 24; i++) { s += v[i]; ss += v[i] * v[i]; }
#pragma unroll
    for (int o = 1; o < 8; o <<= 1) { s += __shfl_xor(s, o); ss += __shfl_xor(ss, o); }
    const float mu = s * (1.f / 192.f);
    const float rstd = rsqrtf(ss * (1.f / 192.f) - mu * mu + 1e-5f);
#pragma unroll
    for (int i = 0; i < 24; i++) {
      const int c = c0 + i;
      wnT[c][n] = f2b((v[i] - mu) * rstd * ld1(g1, c, bf) + ld1(be1, c, bf));
    }
  }
  __syncthreads();

  const float scale = 0.17677669529663687f;

  for (int hp = 0; hp < 3; ++hp) {
    if (tid < 192) {
      const int tg = tid / 24;
      const int cg = tid % 24;
      const int sel = cg >> 3;
      const int hh = (cg >> 2) & 1;
      const int dbase = 8 * (cg & 3);
      const int jcb = sel * 192 + (2 * hp + hh) * 32 + dbase;
      float acc[4][8] = {};
      for (int k = 0; k < 192; k++) {
        const uint2 hw = *reinterpret_cast<const uint2*>(&wnT[k][4 * tg]);
        float a0, a1, a2, a3; up2(hw.x, a0, a1); up2(hw.y, a2, a3);
        float wf[8];
        ld8(wqkv, (size_t)k * 576 + jcb, bf, wf);
#pragma unroll
        for (int jj = 0; jj < 8; jj++) {
          acc[0][jj] += a0 * wf[jj];
          acc[1][jj] += a1 * wf[jj];
          acc[2][jj] += a2 * wf[jj];
          acc[3][jj] += a3 * wf[jj];
        }
      }
      float bb[8];
#pragma unroll
      for (int jj = 0; jj < 8; jj++) bb[jj] = ld1(bqkv, jcb + jj, bf);
      float* dst = (sel == 0) ? &qs[0][0][0] : (sel == 1) ? &ks[0][0][0] : &vs[0][0][0];
#pragma unroll
      for (int t = 0; t < 4; t++) {
        const int n = 4 * tg + t;
        float4 o0, o1;
        o0.x = acc[t][0] + bb[0]; o0.y = acc[t][1] + bb[1];
        o0.z = acc[t][2] + bb[2]; o0.w = acc[t][3] + bb[3];
        o1.x = acc[t][4] + bb[4]; o1.y = acc[t][5] + bb[5];
        o1.z = acc[t][6] + bb[6]; o1.w = acc[t][7] + bb[7];
        float* base = dst + hh * 1024 + n * 32 + dbase;
        *reinterpret_cast<float4*>(base) = o0;
        *reinterpret_cast<float4*>(base + 4) = o1;
      }
    }
    __syncthreads();

    {
      const int hn = tid >> 2, mg = tid & 3;
      const int hh = hn >> 5, n = hn & 31;
      const int hg = 2 * hp + hh;
      float qr[32];
      const float4* qp = reinterpret_cast<const float4*>(&qs[hh][n][0]);
#pragma unroll
      for (int i = 0; i < 8; i++) {
        const float4 t4 = qp[i];
        qr[4 * i] = t4.x; qr[4 * i + 1] = t4.y; qr[4 * i + 2] = t4.z; qr[4 * i + 3] = t4.w;
      }
      const int rn = n >> 3, cn = n & 7;
      const bool rhn = (whi == 15) && (rn >= 2);
      const bool rwn = (wwi == 63) && (cn >= 4);
      float sv[8];
#pragma unroll
      for (int mi = 0; mi < 8; mi++) {
        const int m = 8 * mg + mi;
        const float4* kp = reinterpret_cast<const float4*>(&ks[hh][m][0]);
        float dot = 0.f;
#pragma unroll
        for (int i = 0; i < 8; i++) {
          const float4 kk = kp[i];
          dot += qr[4 * i] * kk.x + qr[4 * i + 1] * kk.y
               + qr[4 * i + 2] * kk.z + qr[4 * i + 3] * kk.w;
        }
        const int rm = m >> 3, cm = m & 7;
        const float bias = ld1(btab, (size_t)((rn - rm + 3) * 15 + (cn - cm + 7)) * 6 + hg, bf);
        const bool rhm = (whi == 15) && (rm >= 2);
        const bool rwm = (wwi == 63) && (cm >= 4);
        const float msk = ((rhn != rhm) || (rwn != rwm)) ? -100.f : 0.f;
        sv[mi] = dot * scale + bias + msk;
      }
      float mx = sv[0];
#pragma unroll
      for (int mi = 1; mi < 8; mi++) mx = fmaxf(mx, sv[mi]);
      mx = fmaxf(mx, __shfl_xor(mx, 1));
      mx = fmaxf(mx, __shfl_xor(mx, 2));
      float sum = 0.f;
#pragma unroll
      for (int mi = 0; mi < 8; mi++) { sv[mi] = __expf(sv[mi] - mx); sum += sv[mi]; }
      sum += __shfl_xor(sum, 1);
      sum += __shfl_xor(sum, 2);
      const float inv = 1.f / sum;
      float4 p0, p1;
      p0.x = sv[0] * inv; p0.y = sv[1] * inv; p0.z = sv[2] * inv; p0.w = sv[3] * inv;
      p1.x = sv[4] * inv; p1.y = sv[5] * inv; p1.z = sv[6] * inv; p1.w = sv[7] * inv;
      *reinterpret_cast<float4*>(&Ps[hh][n][8 * mg]) = p0;
      *reinterpret_cast<float4*>(&Ps[hh][n][8 * mg + 4]) = p1;
    }
    __syncthreads();

    {
      const int hn = tid >> 2, mg = tid & 3;
      const int hh = hn >> 5, n = hn & 31, d0 = 8 * mg;
      const int hg = 2 * hp + hh;
      float pr[32];
      const float4* pp = reinterpret_cast<const float4*>(&Ps[hh][n][0]);
#pragma unroll
      for (int i = 0; i < 8; i++) {
        const float4 t4 = pp[i];
        pr[4 * i] = t4.x; pr[4 * i + 1] = t4.y; pr[4 * i + 2] = t4.z; pr[4 * i + 3] = t4.w;
      }
      float acc[8] = {};
#pragma unroll
      for (int m = 0; m < 32; m++) {
        const float4 v0 = *reinterpret_cast<const float4*>(&vs[hh][m][d0]);
        const float4 v1 = *reinterpret_cast<const float4*>(&vs[hh][m][d0 + 4]);
        const float p = pr[m];
        acc[0] += p * v0.x; acc[1] += p * v0.y; acc[2] += p * v0.z; acc[3] += p * v0.w;
        acc[4] += p * v1.x; acc[5] += p * v1.y; acc[6] += p * v1.z; acc[7] += p * v1.w;
      }
#pragma unroll
      for (int j = 0; j < 8; j++) aoT[hg * 32 + d0 + j][n] = f2b(acc[j]);
    }
    __syncthreads();
  }

  {
    const int tg = tid >> 5, cg = tid & 31;
    const int j0 = 6 * cg;
    float bb[6];
#pragma unroll
    for (int j = 0; j < 6; j++) bb[j] = ld1(bproj, j0 + j, bf);
    float acc[4][6] = {};
    for (int k = 0; k < 192; k++) {
      const uint2 aw = *reinterpret_cast<const uint2*>(&aoT[k][4 * tg]);
      float a0, a1, a2, a3; up2(aw.x, a0, a1); up2(aw.y, a2, a3);
      float wf[6];
      const size_t wi = (size_t)k * 192 + j0;
      ld2(wproj, wi,     bf, wf[0], wf[1]);
      ld2(wproj, wi + 2, bf, wf[2], wf[3]);
      ld2(wproj, wi + 4, bf, wf[4], wf[5]);
#pragma unroll
      for (int jj = 0; jj < 6; jj++) {
        acc[0][jj] += a0 * wf[jj];
        acc[1][jj] += a1 * wf[jj];
        acc[2][jj] += a2 * wf[jj];
        acc[3][jj] += a3 * wf[jj];
      }
    }
#pragma unroll
    for (int t = 0; t < 4; t++) {
      const size_t gt = (size_t)gtok(4 * tg + t);
      const size_t xb = gt * 192 + j0;
      float xv[6];
      ld2(x, xb,     bf, xv[0], xv[1]);
      ld2(x, xb + 2, bf, xv[2], xv[3]);
      ld2(x, xb + 4, bf, xv[4], xv[5]);
#pragma unroll
      for (int q = 0; q < 3; q++) {
        const float r0 = xv[2 * q]     + acc[t][2 * q]     + bb[2 * q];
        const float r1 = xv[2 * q + 1] + acc[t][2 * q + 1] + bb[2 * q + 1];
        st2(out, xb + 2 * q, bf, r0, r1);
      }
    }
  }
}

// ---------------------------------------------------------------------------
// Kernel B (MFMA): MLP block, in-place on d_out. 64 tokens/block, 256 thr.
// out = x1 + gelu(LN2(x1) @ w1 + bm1) @ w2 + bm2
// MFMA 16x16x32 bf16. A-frag: A[m=lane&15][k=quad*8+j] (8 contiguous k).
// B-frag: B[k=quad*8+j][n=lane&15]  -> transposed weights, 8 contiguous k.
// C/D:    D[row=quad*4+reg][col=lane&15].
// Hidden (768) processed in 4 chunks of 192 through LDS, never materialized.
// ---------------------------------------------------------------------------
__launch_bounds__(256, 2)
__global__ void swin_mlp_mfma(
    const void* __restrict__ xp,   // original x, dtype probe only
    void* __restrict__ io, const void* __restrict__ g2, const void* __restrict__ be2,
    const u16* __restrict__ w1t,   // [768][192] bf16 (transposed, in ws)
    const void* __restrict__ bm1,
    const u16* __restrict__ w2t,   // [192][768] bf16 (transposed, in ws)
    const void* __restrict__ bm2)
{
  // stride 200 bf16 = 400 B = 100 dwords; 100 % 4 == 0 (16B-aligned rows),
  // 100 % 32 == 4 -> 2-way bank alias on ds_read_b128 (free).
  __shared__ __align__(16) u16 Xn[64][200];   // LN2 out, [token][chan]
  __shared__ __align__(16) u16 X2[64][200];   // gelu(hidden chunk), [token][h]

  const bool bf = probe_bf16(xp);
  const int tid = threadIdx.x;
  const size_t tok0 = (size_t)blockIdx.x * 64;

  // ---- LN2 -> Xn ----
  {
    const int t = tid >> 2, g = tid & 3;
    const int c0 = 48 * g;
    const size_t base = (tok0 + t) * 192 + c0;
    float v[48];
#pragma unroll
    for (int i = 0; i < 6; i++) ld8(io, base + 8 * i, bf, v + 8 * i);
    float s = 0.f, ss = 0.f;
#pragma unroll
    for (int i = 0; i < 48; i++) { s += v[i]; ss += v[i] * v[i]; }
#pragma unroll
    for (int o = 1; o < 4; o <<= 1) { s += __shfl_xor(s, o); ss += __shfl_xor(ss, o); }
    const float mu = s * (1.f / 192.f);
    const float rstd = rsqrtf(ss * (1.f / 192.f) - mu * mu + 1e-5f);
    u32* dst = reinterpret_cast<u32*>(&Xn[t][c0]);
#pragma unroll
    for (int i = 0; i < 24; i++) {
      const int c = c0 + 2 * i;
      const float r0 = (v[2 * i]     - mu) * rstd * ld1(g2, c,     bf) + ld1(be2, c,     bf);
      const float r1 = (v[2 * i + 1] - mu) * rstd * ld1(g2, c + 1, bf) + ld1(be2, c + 1, bf);
      dst[i] = (u32)f2b(r0) | ((u32)f2b(r1) << 16);
    }
  }
  __syncthreads();

  const int wave = tid >> 6;
  const int lane = tid & 63;
  const int col  = lane & 15;     // MFMA n / C-col
  const int quad = lane >> 4;     // MFMA k-group / C-row-group

  f32x4 acc2[4][3];
#pragma unroll
  for (int mt = 0; mt < 4; mt++)
#pragma unroll
    for (int nt = 0; nt < 3; nt++) acc2[mt][nt] = (f32x4){0.f, 0.f, 0.f, 0.f};

  for (int ch = 0; ch < 4; ++ch) {
    // ---- GEMM1: hid[t][j] for j in chunk (192 wide); wave owns 48 j-cols ----
    f32x4 acc1[4][3];
#pragma unroll
    for (int mt = 0; mt < 4; mt++)
#pragma unroll
      for (int nt = 0; nt < 3; nt++) acc1[mt][nt] = (f32x4){0.f, 0.f, 0.f, 0.f};

    const int jbase = ch * 192 + wave * 48;        // global hidden col base
#pragma unroll
    for (int ks = 0; ks < 6; ks++) {
      short8 bfrg[3], afrg[4];
#pragma unroll
      for (int nt = 0; nt < 3; nt++)
        bfrg[nt] = gld16(w1t + (size_t)(jbase + nt * 16 + col) * 192 + ks * 32 + quad * 8);
#pragma unroll
      for (int mt = 0; mt < 4; mt++)
        afrg[mt] = lds16(&Xn[16 * mt + col][ks * 32 + quad * 8]);
#pragma unroll
      for (int mt = 0; mt < 4; mt++)
#pragma unroll
        for (int nt = 0; nt < 3; nt++)
          acc1[mt][nt] = __builtin_amdgcn_mfma_f32_16x16x32_bf16(
              afrg[mt], bfrg[nt], acc1[mt][nt], 0, 0, 0);
    }

    // ---- GELU + store chunk to X2 ----
#pragma unroll
    for (int nt = 0; nt < 3; nt++) {
      const float b1 = ld1(bm1, jbase + nt * 16 + col, bf);
      const int jl = wave * 48 + nt * 16 + col;    // 0..191 within chunk
#pragma unroll
      for (int mt = 0; mt < 4; mt++)
#pragma unroll
        for (int r = 0; r < 4; r++) {
          const int t = 16 * mt + quad * 4 + r;
          X2[t][jl] = f2b(gelu_t(acc1[mt][nt][r] + b1));
        }
    }
    __syncthreads();

    // ---- GEMM2 partial: acc2[t][c] += gelu_chunk @ w2_chunk ----
#pragma unroll
    for (int ks = 0; ks < 6; ks++) {
      short8 bfrg[3], afrg[4];
#pragma unroll
      for (int nt = 0; nt < 3; nt++)
        bfrg[nt] = gld16(w2t + (size_t)(wave * 48 + nt * 16 + col) * 768
                              + ch * 192 + ks * 32 + quad * 8);
#pragma unroll
      for (int mt = 0; mt < 4; mt++)
        afrg[mt] = lds16(&X2[16 * mt + col][ks * 32 + quad * 8]);
#pragma unroll
      for (int mt = 0; mt < 4; mt++)
#pragma unroll
        for (int nt = 0; nt < 3; nt++)
          acc2[mt][nt] = __builtin_amdgcn_mfma_f32_16x16x32_bf16(
              afrg[mt], bfrg[nt], acc2[mt][nt], 0, 0, 0);
    }
    __syncthreads();
  }

  // ---- epilogue: + bm2 + x1 residual, write back (per-lane RMW, race-free) ----
#pragma unroll
  for (int nt = 0; nt < 3; nt++) {
    const int c = wave * 48 + nt * 16 + col;
    const float b2 = ld1(bm2, c, bf);
#pragma unroll
    for (int mt = 0; mt < 4; mt++)
#pragma unroll
      for (int r = 0; r < 4; r++) {
        const int t = 16 * mt + quad * 4 + r;
        const size_t idx = (tok0 + t) * 192 + c;
        st1(io, idx, bf, acc2[mt][nt][r] + b2 + ld1(io, idx, bf));
      }
  }
}

extern "C" void kernel_launch(void* const* d_in, const int* in_sizes, int n_in,
                              void* d_out, int out_size, void* d_ws, size_t ws_size,
                              hipStream_t stream) {
  const void* x     = d_in[0];
  const void* g1    = d_in[3];
  const void* be1   = d_in[4];
  const void* wqkv  = d_in[5];
  const void* bqkv  = d_in[6];
  const void* wproj = d_in[7];
  const void* bproj = d_in[8];
  const void* btab  = d_in[9];
  const void* g2    = d_in[10];
  const void* be2   = d_in[11];
  const void* w1    = d_in[12];
  const void* bm1   = d_in[13];
  const void* w2    = d_in[14];
  const void* bm2   = d_in[15];

  u16* ws = (u16*)d_ws;                 // w1t @0 (147456 elems), w2t @147456

  // 1) transpose weights into ws (294912 elems, bf16)
  transpose_weights<<<1152, 256, 0, stream>>>(w1, w2, ws);
  // 2) attention: one block per window, writes x1 into d_out
  swin_attn_kernel<<<8192, 256, 0, stream>>>(x, g1, be1, wqkv, bqkv, wproj, bproj, btab, d_out);
  // 3) MLP (MFMA), in-place on d_out
  swin_mlp_mfma<<<4096, 256, 0, stream>>>(x, d_out, g2, be2, ws, bm1, ws + 147456, bm2);
}